// Round 1
// baseline (778.290 us; speedup 1.0000x reference)
//
#include <hip/hip_runtime.h>
#include <math.h>

#define P 13
#define THREADS 256
#define ROWS_PER_TILE 256
#define TILE_ELEMS (ROWS_PER_TILE * P)     // 3328 floats = 13312 B
#define TILE_VEC4 (TILE_ELEMS / 4)         // 832 float4 = 256*3 + 64
#define TAIL_VEC4 (TILE_VEC4 - 3 * THREADS) // 64
#define GRID_BLOCKS 2048                   // ~8 blocks/CU * 256 CU, grid-stride

__global__ __launch_bounds__(THREADS)
void chordal_softmax_kernel(const float* __restrict__ x,
                            const float* __restrict__ w,
                            float* __restrict__ out,
                            int ntiles, int nrows) {
    __shared__ float tile[TILE_ELEMS];
    __shared__ float wperm[12 * P];        // permuted weight per root_pc

    const int tid = threadIdx.x;
    const int total = nrows * P;           // 122.7M < 2^31: 32-bit safe

    // Build the 12x13 permuted-weight table once per block.
    // wperm[r][j] = w[(j - r) mod 12] for j<12; w[12] for j==12.
    if (tid < 12 * P) {
        int r = tid / P;
        int j = tid - r * P;
        wperm[tid] = (j < 12) ? w[(j + 12 - r) % 12] : w[12];
    }

    int t = blockIdx.x;
    if (t >= ntiles) return;
    const int stride = gridDim.x;

    // ---- Prologue: prefetch tile t into registers (depth-1 pipeline) ----
    float4 r0, r1, r2, r3;
    {
        const int e0 = t * TILE_ELEMS;
        if (e0 + TILE_ELEMS <= total) {
            const float4* in4 = reinterpret_cast<const float4*>(x + e0);
            r0 = in4[tid];
            r1 = in4[tid + THREADS];
            r2 = in4[tid + 2 * THREADS];
            if (tid < TAIL_VEC4) r3 = in4[tid + 3 * THREADS];
        }
    }

    while (true) {
        const int e0 = t * TILE_ELEMS;
        const bool full = (e0 + TILE_ELEMS <= total);

        // ---- Commit staged registers (or slow-path load for ragged tail) ----
        if (full) {
            float4* t4 = reinterpret_cast<float4*>(tile);
            t4[tid] = r0;
            t4[tid + THREADS] = r1;
            t4[tid + 2 * THREADS] = r2;
            if (tid < TAIL_VEC4) t4[tid + 3 * THREADS] = r3;
        } else {
            for (int i = tid; i < TILE_ELEMS; i += THREADS) {
                int g = e0 + i;
                tile[i] = (g < total) ? x[g] : 0.0f;
            }
        }

        // ---- Issue next tile's loads NOW; they land during compute+store ----
        const int tn = t + stride;
        const bool have_next = (tn < ntiles);
        if (have_next && (tn * TILE_ELEMS + TILE_ELEMS <= total)) {
            const float4* in4 = reinterpret_cast<const float4*>(x + tn * TILE_ELEMS);
            r0 = in4[tid];
            r1 = in4[tid + THREADS];
            r2 = in4[tid + 2 * THREADS];
            if (tid < TAIL_VEC4) r3 = in4[tid + 3 * THREADS];
        }

        __syncthreads();   // tile (and wperm on iter 0) visible to all

        // ---- Per-thread row softmax ----
        const int row = t * ROWS_PER_TILE + tid;
        if (row < nrows) {
            const int root = (row % 144) / 12;   // 0..11
            const float* wp = &wperm[root * P];

            float v[P];
            float m = -1e30f;
            #pragma unroll
            for (int j = 0; j < P; ++j) {
                v[j] = tile[tid * P + j] * wp[j];
                m = fmaxf(m, v[j]);
            }
            float s = 0.0f;
            #pragma unroll
            for (int j = 0; j < P; ++j) {
                v[j] = __expf(v[j] - m);
                s += v[j];
            }
            const float inv = 1.0f / s;
            #pragma unroll
            for (int j = 0; j < P; ++j) {
                tile[tid * P + j] = v[j] * inv;
            }
        }
        __syncthreads();   // results visible for staged store

        // ---- Stage LDS -> global (coalesced float4) ----
        if (full) {
            float4* o4 = reinterpret_cast<float4*>(out + e0);
            const float4* t4 = reinterpret_cast<const float4*>(tile);
            o4[tid] = t4[tid];
            o4[tid + THREADS] = t4[tid + THREADS];
            o4[tid + 2 * THREADS] = t4[tid + 2 * THREADS];
            if (tid < TAIL_VEC4) o4[tid + 3 * THREADS] = t4[tid + 3 * THREADS];
        } else {
            for (int i = tid; i < TILE_ELEMS; i += THREADS) {
                int g = e0 + i;
                if (g < total) out[g] = tile[i];
            }
        }

        if (!have_next) break;
        t = tn;
        // A wave past its global_stores has finished its ds_reads (register
        // dependency). This barrier makes `tile` safe to overwrite next iter.
        __syncthreads();
    }
}

extern "C" void kernel_launch(void* const* d_in, const int* in_sizes, int n_in,
                              void* d_out, int out_size, void* d_ws, size_t ws_size,
                              hipStream_t stream) {
    const float* x = (const float*)d_in[0];   // [B, L, P] f32
    const float* w = (const float*)d_in[1];   // [P] f32
    float* out = (float*)d_out;               // [B, L, P] f32

    const long long total = (long long)in_sizes[0];
    const long long nrowsll = total / P;      // B*L = 9,437,184
    const int nrows = (int)nrowsll;
    const int ntiles = (int)((nrowsll + ROWS_PER_TILE - 1) / ROWS_PER_TILE);
    const int blocks = ntiles < GRID_BLOCKS ? ntiles : GRID_BLOCKS;

    chordal_softmax_kernel<<<blocks, THREADS, 0, stream>>>(x, w, out, ntiles, nrows);
}